// Round 1
// baseline (38.465 us; speedup 1.0000x reference)
//
#include <hip/hip_runtime.h>

// YOLO loss: S=28, B=2, NUM_CLASSES=20, L_COORD=5, L_NOOBJ=0.5, N=1024
// Inputs (fp32 unless noted):
//   d_in[0] pred_tensor  (N,28,28,30)
//   d_in[1] target_boxes (N,28,28,4)
//   d_in[2] target_cls   (N,28,28,20)
//   d_in[3] has_object_map (N,28,28) bool -> int32 on device
// Output: 5 floats [total, reg, contain, noobj, cls]

__device__ inline float wave_reduce(float v) {
    #pragma unroll
    for (int off = 32; off > 0; off >>= 1)
        v += __shfl_down(v, off, 64);
    return v;
}

__global__ void __launch_bounds__(256) yolo_partial(
    const float* __restrict__ pred,
    const float* __restrict__ tbox,
    const float* __restrict__ tcls,
    const int*  __restrict__ mask,
    float* __restrict__ partial, int ncells)
{
    const float inv_s = 1.0f / 28.0f;
    float s_cls = 0.f, s_noobj = 0.f, s_contain = 0.f, s_reg = 0.f;

    for (int cell = blockIdx.x * blockDim.x + threadIdx.x; cell < ncells;
         cell += gridDim.x * blockDim.x) {
        // pred cell: 30 floats, base 8B-aligned (120B stride) -> 15x float2
        const float2* p2 = (const float2*)pred + (size_t)cell * 15;
        float2 v0 = p2[0], v1 = p2[1], v2 = p2[2], v3 = p2[3], v4 = p2[4];
        // box0 = (v0.x, v0.y, v1.x, v1.y, conf v2.x)
        // box1 = (v2.y, v3.x, v3.y, v4.x, conf v4.y)

        float m = mask[cell] ? 1.0f : 0.0f;

        // ---- class loss: pred floats 10..29 (float2 idx 5..14) vs tcls (float4 aligned)
        float pc[20];
        #pragma unroll
        for (int k = 0; k < 10; k++) { float2 t = p2[5 + k]; pc[2*k] = t.x; pc[2*k+1] = t.y; }
        const float4* c4 = (const float4*)tcls + (size_t)cell * 5;
        float cl = 0.f;
        #pragma unroll
        for (int k = 0; k < 5; k++) {
            float4 t = c4[k];
            float d0 = pc[4*k+0] - t.x, d1 = pc[4*k+1] - t.y;
            float d2 = pc[4*k+2] - t.z, d3 = pc[4*k+3] - t.w;
            cl += d0*d0 + d1*d1 + d2*d2 + d3*d3;
        }
        s_cls += cl * m;

        // ---- no-object loss (x0.5 applied in final kernel)
        float conf0 = v2.x, conf1 = v4.y;
        s_noobj += (conf0*conf0 + conf1*conf1) * (1.0f - m);

        // ---- target box -> xyxy
        float4 tb = ((const float4*)tbox)[cell];
        float tx = tb.x * inv_s, ty = tb.y * inv_s;
        float tx1 = tx - 0.5f*tb.z, ty1 = ty - 0.5f*tb.w;
        float tx2 = tx + 0.5f*tb.z, ty2 = ty + 0.5f*tb.w;
        float area_t = (tx2 - tx1) * (ty2 - ty1);

        // ---- IoU of both pred boxes vs target (same formula as ref)
        float bxv[2] = {v0.x, v2.y}, byv[2] = {v0.y, v3.x};
        float bwv[2] = {v1.x, v3.y}, bhv[2] = {v1.y, v4.x};
        float confv[2] = {conf0, conf1};
        float iou[2];
        #pragma unroll
        for (int b = 0; b < 2; b++) {
            float px = bxv[b] * inv_s, py = byv[b] * inv_s;
            float px1 = px - 0.5f*bwv[b], py1 = py - 0.5f*bhv[b];
            float px2 = px + 0.5f*bwv[b], py2 = py + 0.5f*bhv[b];
            float ltx = fmaxf(px1, tx1), lty = fmaxf(py1, ty1);
            float rbx = fminf(px2, tx2), rby = fminf(py2, ty2);
            float w = fmaxf(rbx - ltx, 0.f), h = fmaxf(rby - lty, 0.f);
            float inter = w * h;
            float area_p = (px2 - px1) * (py2 - py1);
            iou[b] = inter / (area_p + area_t - inter);
        }
        // argmax picks first index on ties -> strict greater-than for box1
        int bi = (iou[1] > iou[0]) ? 1 : 0;
        float biou = fmaxf(iou[0], iou[1]);

        float bbx = bxv[bi], bby = byv[bi], bbw = bwv[bi], bbh = bhv[bi], bconf = confv[bi];

        // ---- regression loss (x5 applied in final kernel)
        float dx = bbx - tb.x, dy = bby - tb.y;
        float center = dx*dx + dy*dy;
        float sw = sqrtf(fmaxf(bbw, 0.f)) - sqrtf(tb.z);
        float sh = sqrtf(fmaxf(bbh, 0.f)) - sqrtf(tb.w);
        s_reg += (center + sw*sw + sh*sh) * m;

        // ---- containment loss
        float dc = bconf - biou;
        s_contain += dc * dc * m;
    }

    // block reduce: 4 waves x 4 sums
    __shared__ float red[4][4];
    int lane = threadIdx.x & 63, wid = threadIdx.x >> 6;
    s_cls = wave_reduce(s_cls);
    s_noobj = wave_reduce(s_noobj);
    s_contain = wave_reduce(s_contain);
    s_reg = wave_reduce(s_reg);
    if (lane == 0) {
        red[wid][0] = s_cls; red[wid][1] = s_noobj;
        red[wid][2] = s_contain; red[wid][3] = s_reg;
    }
    __syncthreads();
    if (threadIdx.x < 4) {
        float acc = red[0][threadIdx.x] + red[1][threadIdx.x]
                  + red[2][threadIdx.x] + red[3][threadIdx.x];
        partial[(size_t)blockIdx.x * 4 + threadIdx.x] = acc;
    }
}

__global__ void __launch_bounds__(256) yolo_final(
    const float* __restrict__ partial, int nblocks, float* __restrict__ out)
{
    float s0 = 0.f, s1 = 0.f, s2 = 0.f, s3 = 0.f;
    for (int i = threadIdx.x; i < nblocks; i += blockDim.x) {
        s0 += partial[i*4+0]; s1 += partial[i*4+1];
        s2 += partial[i*4+2]; s3 += partial[i*4+3];
    }
    __shared__ float red[4][4];
    int lane = threadIdx.x & 63, wid = threadIdx.x >> 6;
    s0 = wave_reduce(s0); s1 = wave_reduce(s1);
    s2 = wave_reduce(s2); s3 = wave_reduce(s3);
    if (lane == 0) { red[wid][0]=s0; red[wid][1]=s1; red[wid][2]=s2; red[wid][3]=s3; }
    __syncthreads();
    if (threadIdx.x == 0) {
        float cls = 0.f, noobj = 0.f, contain = 0.f, reg = 0.f;
        #pragma unroll
        for (int w = 0; w < 4; w++) {
            cls += red[w][0]; noobj += red[w][1];
            contain += red[w][2]; reg += red[w][3];
        }
        noobj *= 0.5f;   // L_NOOBJ
        reg   *= 5.0f;   // L_COORD
        float total = (cls + noobj + contain + reg) / 1024.0f;
        out[0] = total; out[1] = reg; out[2] = contain;
        out[3] = noobj; out[4] = cls;
    }
}

extern "C" void kernel_launch(void* const* d_in, const int* in_sizes, int n_in,
                              void* d_out, int out_size, void* d_ws, size_t ws_size,
                              hipStream_t stream) {
    const float* pred = (const float*)d_in[0];
    const float* tbox = (const float*)d_in[1];
    const float* tcls = (const float*)d_in[2];
    const int*   mask = (const int*)d_in[3];

    int ncells = in_sizes[3];                 // N * S * S = 802816
    int nblocks = (ncells + 255) / 256;       // 3136 -> one cell per thread
    int maxblocks = (int)(ws_size / (4 * sizeof(float)));
    if (nblocks > maxblocks) nblocks = maxblocks;
    if (nblocks < 1) nblocks = 1;

    yolo_partial<<<nblocks, 256, 0, stream>>>(
        pred, tbox, tcls, mask, (float*)d_ws, ncells);
    yolo_final<<<1, 256, 0, stream>>>((float*)d_ws, nblocks, (float*)d_out);
}

// Round 2
// 35.549 us; speedup vs baseline: 1.0820x; 1.0820x over previous
//
#include <hip/hip_runtime.h>

// YOLO loss: S=28, B=2, NUM_CLASSES=20, L_COORD=5, L_NOOBJ=0.5, N=1024
// Inputs (fp32 unless noted):
//   d_in[0] pred_tensor  (N,28,28,30)
//   d_in[1] target_boxes (N,28,28,4)
//   d_in[2] target_cls   (N,28,28,20)
//   d_in[3] has_object_map (N,28,28) bool -> int32 on device
// Output: 5 floats [total, reg, contain, noobj, cls]
//
// R2: pred (120B/cell, 8B-aligned stride) is LDS-staged with coalesced
// float4 loads to fix the latency-bound strided access seen in R1
// (VALUBusy 7.9%, hbm 21%, VGPR 32 -> no MLP).

__device__ inline float wave_reduce(float v) {
    #pragma unroll
    for (int off = 32; off > 0; off >>= 1)
        v += __shfl_down(v, off, 64);
    return v;
}

__global__ void __launch_bounds__(256) yolo_partial(
    const float* __restrict__ pred,
    const float* __restrict__ tbox,
    const float* __restrict__ tcls,
    const int*  __restrict__ mask,
    float* __restrict__ partial, int ncells)
{
    __shared__ float sp[7680];              // 256 cells x 30 floats = 30720 B
    const float inv_s = 1.0f / 28.0f;

    const int base = blockIdx.x * 256;
    const int nc   = min(256, ncells - base);   // cells this block owns

    // ---- stage pred chunk into LDS, fully coalesced ----
    if (nc == 256) {
        // 1920 float4s; 8 independent dwordx4 loads per thread
        const float4* g4 = (const float4*)pred + (size_t)blockIdx.x * 1920;
        float4* s4 = (float4*)sp;
        #pragma unroll
        for (int i = 0; i < 8; ++i) {
            int idx = threadIdx.x + i * 256;
            if (idx < 1920) s4[idx] = g4[idx];
        }
    } else {
        // generic tail (unused for N=1024: 3136 full blocks)
        for (int w = threadIdx.x; w < nc * 30; w += 256)
            sp[w] = pred[(size_t)base * 30 + w];
    }
    __syncthreads();

    float s_cls = 0.f, s_noobj = 0.f, s_contain = 0.f, s_reg = 0.f;

    const int cell = base + threadIdx.x;
    if (cell < ncells) {
        // pred cell from LDS: 15x float2 (8B aligned: tid*120B)
        const float2* p2 = (const float2*)(sp + threadIdx.x * 30);
        float2 v0 = p2[0], v1 = p2[1], v2 = p2[2], v3 = p2[3], v4 = p2[4];
        // box0 = (v0.x, v0.y, v1.x, v1.y, conf v2.x)
        // box1 = (v2.y, v3.x, v3.y, v4.x, conf v4.y)

        float m = mask[cell] ? 1.0f : 0.0f;

        // ---- class loss: pred floats 10..29 vs tcls (float4 aligned, 80B/cell)
        float pc[20];
        #pragma unroll
        for (int k = 0; k < 10; k++) { float2 t = p2[5 + k]; pc[2*k] = t.x; pc[2*k+1] = t.y; }
        const float4* c4 = (const float4*)tcls + (size_t)cell * 5;
        float cl = 0.f;
        #pragma unroll
        for (int k = 0; k < 5; k++) {
            float4 t = c4[k];
            float d0 = pc[4*k+0] - t.x, d1 = pc[4*k+1] - t.y;
            float d2 = pc[4*k+2] - t.z, d3 = pc[4*k+3] - t.w;
            cl += d0*d0 + d1*d1 + d2*d2 + d3*d3;
        }
        s_cls = cl * m;

        // ---- no-object loss (x0.5 applied in final kernel)
        float conf0 = v2.x, conf1 = v4.y;
        s_noobj = (conf0*conf0 + conf1*conf1) * (1.0f - m);

        // ---- target box -> xyxy
        float4 tb = ((const float4*)tbox)[cell];
        float tx = tb.x * inv_s, ty = tb.y * inv_s;
        float tx1 = tx - 0.5f*tb.z, ty1 = ty - 0.5f*tb.w;
        float tx2 = tx + 0.5f*tb.z, ty2 = ty + 0.5f*tb.w;
        float area_t = (tx2 - tx1) * (ty2 - ty1);

        // ---- IoU of both pred boxes vs target (same formula as ref)
        float bxv[2] = {v0.x, v2.y}, byv[2] = {v0.y, v3.x};
        float bwv[2] = {v1.x, v3.y}, bhv[2] = {v1.y, v4.x};
        float confv[2] = {conf0, conf1};
        float iou[2];
        #pragma unroll
        for (int b = 0; b < 2; b++) {
            float px = bxv[b] * inv_s, py = byv[b] * inv_s;
            float px1 = px - 0.5f*bwv[b], py1 = py - 0.5f*bhv[b];
            float px2 = px + 0.5f*bwv[b], py2 = py + 0.5f*bhv[b];
            float ltx = fmaxf(px1, tx1), lty = fmaxf(py1, ty1);
            float rbx = fminf(px2, tx2), rby = fminf(py2, ty2);
            float w = fmaxf(rbx - ltx, 0.f), h = fmaxf(rby - lty, 0.f);
            float inter = w * h;
            float area_p = (px2 - px1) * (py2 - py1);
            iou[b] = inter / (area_p + area_t - inter);
        }
        // argmax picks first index on ties -> strict greater-than for box1
        int bi = (iou[1] > iou[0]) ? 1 : 0;
        float biou = fmaxf(iou[0], iou[1]);

        float bbx = bxv[bi], bby = byv[bi], bbw = bwv[bi], bbh = bhv[bi], bconf = confv[bi];

        // ---- regression loss (x5 applied in final kernel)
        float dx = bbx - tb.x, dy = bby - tb.y;
        float center = dx*dx + dy*dy;
        float sw = sqrtf(fmaxf(bbw, 0.f)) - sqrtf(tb.z);
        float sh = sqrtf(fmaxf(bbh, 0.f)) - sqrtf(tb.w);
        s_reg = (center + sw*sw + sh*sh) * m;

        // ---- containment loss
        float dc = bconf - biou;
        s_contain = dc * dc * m;
    }

    // block reduce: 4 waves x 4 sums
    __shared__ float red[4][4];
    int lane = threadIdx.x & 63, wid = threadIdx.x >> 6;
    s_cls = wave_reduce(s_cls);
    s_noobj = wave_reduce(s_noobj);
    s_contain = wave_reduce(s_contain);
    s_reg = wave_reduce(s_reg);
    if (lane == 0) {
        red[wid][0] = s_cls; red[wid][1] = s_noobj;
        red[wid][2] = s_contain; red[wid][3] = s_reg;
    }
    __syncthreads();
    if (threadIdx.x < 4) {
        float acc = red[0][threadIdx.x] + red[1][threadIdx.x]
                  + red[2][threadIdx.x] + red[3][threadIdx.x];
        partial[(size_t)blockIdx.x * 4 + threadIdx.x] = acc;
    }
}

__global__ void __launch_bounds__(256) yolo_final(
    const float* __restrict__ partial, int nblocks, float* __restrict__ out)
{
    float s0 = 0.f, s1 = 0.f, s2 = 0.f, s3 = 0.f;
    for (int i = threadIdx.x; i < nblocks; i += blockDim.x) {
        s0 += partial[i*4+0]; s1 += partial[i*4+1];
        s2 += partial[i*4+2]; s3 += partial[i*4+3];
    }
    __shared__ float red[4][4];
    int lane = threadIdx.x & 63, wid = threadIdx.x >> 6;
    s0 = wave_reduce(s0); s1 = wave_reduce(s1);
    s2 = wave_reduce(s2); s3 = wave_reduce(s3);
    if (lane == 0) { red[wid][0]=s0; red[wid][1]=s1; red[wid][2]=s2; red[wid][3]=s3; }
    __syncthreads();
    if (threadIdx.x == 0) {
        float cls = 0.f, noobj = 0.f, contain = 0.f, reg = 0.f;
        #pragma unroll
        for (int w = 0; w < 4; w++) {
            cls += red[w][0]; noobj += red[w][1];
            contain += red[w][2]; reg += red[w][3];
        }
        noobj *= 0.5f;   // L_NOOBJ
        reg   *= 5.0f;   // L_COORD
        float total = (cls + noobj + contain + reg) / 1024.0f;
        out[0] = total; out[1] = reg; out[2] = contain;
        out[3] = noobj; out[4] = cls;
    }
}

extern "C" void kernel_launch(void* const* d_in, const int* in_sizes, int n_in,
                              void* d_out, int out_size, void* d_ws, size_t ws_size,
                              hipStream_t stream) {
    const float* pred = (const float*)d_in[0];
    const float* tbox = (const float*)d_in[1];
    const float* tcls = (const float*)d_in[2];
    const int*   mask = (const int*)d_in[3];

    int ncells = in_sizes[3];                 // N * S * S = 802816
    int nblocks = (ncells + 255) / 256;       // 3136 -> one cell per thread
    int maxblocks = (int)(ws_size / (4 * sizeof(float)));
    if (nblocks > maxblocks) nblocks = maxblocks;
    if (nblocks < 1) nblocks = 1;

    yolo_partial<<<nblocks, 256, 0, stream>>>(
        pred, tbox, tcls, mask, (float*)d_ws, ncells);
    yolo_final<<<1, 256, 0, stream>>>((float*)d_ws, nblocks, (float*)d_out);
}